// Round 13
// baseline (1005.397 us; speedup 1.0000x reference)
//
#include <hip/hip_runtime.h>
#include <hip/hip_bf16.h>
#include <stdint.h>

// Problem constants
constexpr int NB = 2;        // batch
constexpr int NT = 4096;     // seq len
constexpr int NH = 16;       // heads
constexpr int ND = 128;      // head dim
constexpr int HID = NH * ND;         // 2048
constexpr int QKV_N = 3 * HID;       // 6144
constexpr int ROWS = NB * NT;        // 8192
constexpr int CHUNK = 64;            // scan chunk length
constexpr int NCH = NT / CHUNK;      // 64 chunks

typedef __bf16 bf16x8 __attribute__((ext_vector_type(8)));
typedef float  f32x4  __attribute__((ext_vector_type(4)));

__device__ inline unsigned short f2bf(float f) {       // RNE fp32->bf16
    unsigned u = __builtin_bit_cast(unsigned, f);
    u += 0x7fffu + ((u >> 16) & 1u);
    return (unsigned short)(u >> 16);
}
__device__ inline float bf2f(unsigned short b) {
    unsigned u = ((unsigned)b) << 16;
    return __builtin_bit_cast(float, u);
}

// ---------- fused prep: cast x AND transpose both weights (1 launch) ------
// blocks [0,2048): cast x (grid-stride float4)
// blocks [2048, 2048+12288): transpose w_qkv 32x32 tiles
// blocks [2048+12288, +4096): transpose w_out
constexpr int PREP_CAST_BLK = 2048;
constexpr int PREP_TQ_BLK   = (QKV_N / 32) * (HID / 32);   // 192*64 = 12288
constexpr int PREP_TW_BLK   = (HID / 32) * (HID / 32);     // 64*64  = 4096

__global__ __launch_bounds__(256) void prep_kernel(
        const float* __restrict__ x, const float* __restrict__ w_qkv,
        const float* __restrict__ w_out,
        unsigned short* __restrict__ xb, unsigned short* __restrict__ wqkvT,
        unsigned short* __restrict__ woutT) {
    __shared__ float tile[32][33];
    const int b = blockIdx.x;
    if (b < PREP_CAST_BLK) {
        size_t n4 = (size_t)ROWS * HID / 4;
        size_t i = b * (size_t)blockDim.x + threadIdx.x;
        size_t stride = (size_t)PREP_CAST_BLK * blockDim.x;
        for (; i < n4; i += stride) {
            float4 v = reinterpret_cast<const float4*>(x)[i];
            ushort4 o;
            o.x = f2bf(v.x); o.y = f2bf(v.y); o.z = f2bf(v.z); o.w = f2bf(v.w);
            reinterpret_cast<ushort4*>(xb)[i] = o;
        }
        return;
    }
    const float* in;
    unsigned short* out;
    int R, Cn, tb;
    if (b < PREP_CAST_BLK + PREP_TQ_BLK) {
        tb = b - PREP_CAST_BLK; in = w_qkv; out = wqkvT; R = HID; Cn = QKV_N;
    } else {
        tb = b - PREP_CAST_BLK - PREP_TQ_BLK; in = w_out; out = woutT; R = HID; Cn = HID;
    }
    const int nbx = Cn / 32;
    const int c0 = (tb % nbx) * 32, r0 = (tb / nbx) * 32;
    const int c  = threadIdx.x & 31;
    const int r8 = threadIdx.x >> 5;          // 0..7
    #pragma unroll
    for (int i = 0; i < 32; i += 8)
        tile[r8 + i][c] = in[(size_t)(r0 + r8 + i) * Cn + c0 + c];
    __syncthreads();
    #pragma unroll
    for (int i = 0; i < 32; i += 8)
        out[(size_t)(c0 + r8 + i) * R + r0 + c] = f2bf(tile[c][r8 + i]);
}

// ====== 128x128 4-wave BK=64 GEMM: A via LDS dbuf, B direct-from-global ====
// Round 13: r10 kernel minus the B LDS path. LDS traffic per block-step
// drops 96KB -> 48KB (the r10 limiter: 256 B/cy/CU shared LDS pipe), and
// LDS shrinks to 32 KiB -> FOUR blocks/CU (4 barrier domains). B-fragments
// come straight from global; the XCD-window mapping keeps each B panel
// shared by 8 co-resident blocks -> L2-served (~30 TB/s aggregate, under
// the 34.5 ceiling).

__device__ __forceinline__ void gll(const unsigned short* src, unsigned short* dst) {
    __builtin_amdgcn_global_load_lds(
        (const __attribute__((address_space(1))) void*)src,
        (__attribute__((address_space(3))) void*)dst, 16, 0, 0);
}

// Stage one 128x64 bf16 tile (16 KB): 4 waves x 4 rounds x 8 rows.
__device__ __forceinline__ void stage_t(const unsigned short* G, int K, int k0,
                                        unsigned short* lds, int wid, int lane) {
    const int rbase = wid * 32;
    const int rl = lane >> 3;                        // 0..7 row within group
    const int ce = ((lane & 7) ^ rl) * 8;            // inverse-swizzled col
    #pragma unroll
    for (int j = 0; j < 4; ++j) {
        gll(G + (size_t)(rbase + j * 8 + rl) * K + k0 + ce,
            lds + (rbase + j * 8) * 64);
    }
}

// swizzled ds_read: row r, k-slot kk*4+fq (8 slots of 8 bf16 across BK=64)
__device__ __forceinline__ bf16x8 ld_frag(const unsigned short* tile,
                                          int r, int kk, int fq) {
    int slot = (kk * 4 + fq) ^ (r & 7);
    return *reinterpret_cast<const bf16x8*>(tile + r * 64 + slot * 8);
}

template <typename OUT_T>
__global__ __launch_bounds__(256, 4) void gemm128(
        const unsigned short* __restrict__ A,   // [M][K] bf16
        const unsigned short* __restrict__ Bt,  // [N][K] bf16
        OUT_T* __restrict__ C,                  // [M][N]
        int M, int N, int K, int byc) {
    __shared__ unsigned short As0[128 * 64];
    __shared__ unsigned short As1[128 * 64];

    const int bid = blockIdx.x;
    const int xcd = bid & 7;
    const int c   = bid >> 3;
    const int by  = xcd * byc + (c % byc);   // 8-wide by-band per XCD
    const int bx  = c / byc;                 // column-major within band
    const int tid = threadIdx.x, wid = tid >> 6, lane = tid & 63;
    const int wm  = wid >> 1, wn = wid & 1;         // 2x2 waves, 64x64 each
    const int fr  = lane & 15, fq = lane >> 4;

    const unsigned short* Ag = A  + (size_t)by * 128 * K;
    const unsigned short* Bg = Bt + (size_t)bx * 128 * K;

    // per-lane B base: row = wn*64 + fr (+n*16), col = fq*8 (+kk*32) (+t*64)
    const unsigned short* Bl = Bg + (size_t)(wn * 64 + fr) * K + fq * 8;

    f32x4 acc[4][4] = {};

    stage_t(Ag, K, 0, As0, wid, lane);
    __syncthreads();

    const int NK = K / 64;
    for (int t = 0; t < NK; ++t) {
        const unsigned short* Ac = (t & 1) ? As1 : As0;
        if (t + 1 < NK) {   // prefetch next A K-tile into the other buffer
            unsigned short* An = (t & 1) ? As0 : As1;
            stage_t(Ag, K, (t + 1) * 64, An, wid, lane);
        }
        // B fragments direct from global (L2-hot via XCD window)
        bf16x8 bf[4][2];
        #pragma unroll
        for (int n = 0; n < 4; ++n)
            #pragma unroll
            for (int kk = 0; kk < 2; ++kk)
                bf[n][kk] = *reinterpret_cast<const bf16x8*>(
                    Bl + (size_t)(n * 16) * K + t * 64 + kk * 32);
        bf16x8 af[4][2];
        #pragma unroll
        for (int m = 0; m < 4; ++m) {
            int r = wm * 64 + m * 16 + fr;
            af[m][0] = ld_frag(Ac, r, 0, fq);
            af[m][1] = ld_frag(Ac, r, 1, fq);
        }
        __builtin_amdgcn_s_setprio(1);
        #pragma unroll
        for (int kk = 0; kk < 2; ++kk)
            #pragma unroll
            for (int m = 0; m < 4; ++m)
                #pragma unroll
                for (int n = 0; n < 4; ++n)
                    acc[m][n] = __builtin_amdgcn_mfma_f32_16x16x32_bf16(
                        af[m][kk], bf[n][kk], acc[m][n], 0, 0, 0);
        __builtin_amdgcn_s_setprio(0);
        __syncthreads();
    }

    // C write (verified C/D layout: row = fq*4+r, col = fr)
    const int bm = by * 128, bn = bx * 128;
    #pragma unroll
    for (int m = 0; m < 4; ++m) {
        #pragma unroll
        for (int n = 0; n < 4; ++n) {
            #pragma unroll
            for (int r = 0; r < 4; ++r) {
                int row = bm + wm * 64 + m * 16 + fq * 4 + r;
                int col = bn + wn * 64 + n * 16 + fr;
                float v = acc[m][n][r];
                if constexpr (sizeof(OUT_T) == 2)
                    C[(size_t)row * N + col] = (OUT_T)f2bf(v);
                else
                    C[(size_t)row * N + col] = (OUT_T)v;
            }
        }
    }
}

// ---------------- scan helpers ----------------
__device__ inline float phi_f(float z) { return z > 0.f ? z + 1.f : __expf(z); }
__device__ inline float sigmoid_f(float z) { return 1.f / (1.f + __expf(-z)); }

// Pass 1: per-(b,h,chunk) local scan finals (zero init). qkv bf16.
__global__ void scan_pass1(const unsigned short* __restrict__ qkv,
                           const float* __restrict__ decay_param,
                           float* __restrict__ fkv, float* __restrict__ fk) {
    const int blk = blockIdx.x;
    const int c = blk % NCH;
    const int h = (blk / NCH) % NH;
    const int b = blk / (NCH * NH);
    const int lane = threadIdx.x;
    const float dec = sigmoid_f(decay_param[h]);

    float skv0 = 0.f, skv1 = 0.f, sk0 = 0.f, sk1 = 0.f;
    const unsigned short* base =
        qkv + ((size_t)b * NT + (size_t)c * CHUNK) * QKV_N + h * ND;
    for (int t = 0; t < CHUNK; ++t) {
        const unsigned short* r = base + (size_t)t * QKV_N;
        unsigned kp = *reinterpret_cast<const unsigned*>(r + HID + 2 * lane);
        unsigned vp = *reinterpret_cast<const unsigned*>(r + 2 * HID + 2 * lane);
        float k0 = phi_f(bf2f((unsigned short)(kp & 0xffff)));
        float k1 = phi_f(bf2f((unsigned short)(kp >> 16)));
        float v0 = bf2f((unsigned short)(vp & 0xffff));
        float v1 = bf2f((unsigned short)(vp >> 16));
        skv0 = fmaf(dec, skv0, k0 * v0);
        skv1 = fmaf(dec, skv1, k1 * v1);
        sk0  = fmaf(dec, sk0,  k0);
        sk1  = fmaf(dec, sk1,  k1);
    }
    size_t o = (size_t)blk * ND + 2 * lane;
    *reinterpret_cast<float2*>(&fkv[o]) = make_float2(skv0, skv1);
    *reinterpret_cast<float2*>(&fk[o])  = make_float2(sk0, sk1);
}

// Pass 2: sequential chunk combine; emits carry-ins and final states.
__global__ void scan_pass2(const float* __restrict__ fkv, const float* __restrict__ fk,
                           const float* __restrict__ decay_param,
                           float* __restrict__ ckv, float* __restrict__ ck,
                           float* __restrict__ out_states) {
    const int bh = blockIdx.x;
    const int h = bh % NH;
    const int lane = threadIdx.x;
    const float dec = sigmoid_f(decay_param[h]);
    const float dL = powf(dec, (float)CHUNK);

    float Skv0 = 0.f, Skv1 = 0.f, Sk0 = 0.f, Sk1 = 0.f;
    for (int c = 0; c < NCH; ++c) {
        size_t o = ((size_t)bh * NCH + c) * ND + 2 * lane;
        *reinterpret_cast<float2*>(&ckv[o]) = make_float2(Skv0, Skv1);
        *reinterpret_cast<float2*>(&ck[o])  = make_float2(Sk0, Sk1);
        float2 fv = *reinterpret_cast<const float2*>(&fkv[o]);
        float2 fs = *reinterpret_cast<const float2*>(&fk[o]);
        Skv0 = fmaf(dL, Skv0, fv.x);
        Skv1 = fmaf(dL, Skv1, fv.y);
        Sk0  = fmaf(dL, Sk0,  fs.x);
        Sk1  = fmaf(dL, Sk1,  fs.y);
    }
    size_t so = (size_t)bh * ND + 2 * lane;
    *reinterpret_cast<float2*>(&out_states[so]) = make_float2(Skv0, Skv1);
    *reinterpret_cast<float2*>(&out_states[NB * NH * ND + so]) = make_float2(Sk0, Sk1);
}

// Pass 3: replay with carry-in; writes attn in bf16.
__global__ void scan_pass3(const unsigned short* __restrict__ qkv,
                           const float* __restrict__ decay_param,
                           const float* __restrict__ ckv, const float* __restrict__ ck,
                           unsigned short* __restrict__ attn) {
    const int blk = blockIdx.x;
    const int c = blk % NCH;
    const int h = (blk / NCH) % NH;
    const int b = blk / (NCH * NH);
    const int lane = threadIdx.x;
    const float dec = sigmoid_f(decay_param[h]);

    size_t co = (size_t)blk * ND + 2 * lane;
    float2 cv = *reinterpret_cast<const float2*>(&ckv[co]);
    float2 cs = *reinterpret_cast<const float2*>(&ck[co]);
    float skv0 = cv.x, skv1 = cv.y, sk0 = cs.x, sk1 = cs.y;

    const unsigned short* base =
        qkv + ((size_t)b * NT + (size_t)c * CHUNK) * QKV_N + h * ND;
    unsigned short* abase =
        attn + ((size_t)b * NT + (size_t)c * CHUNK) * HID + h * ND;

    for (int t = 0; t < CHUNK; ++t) {
        const unsigned short* r = base + (size_t)t * QKV_N;
        unsigned qp = *reinterpret_cast<const unsigned*>(r + 2 * lane);
        unsigned kp = *reinterpret_cast<const unsigned*>(r + HID + 2 * lane);
        unsigned vp = *reinterpret_cast<const unsigned*>(r + 2 * HID + 2 * lane);
        float q0 = phi_f(bf2f((unsigned short)(qp & 0xffff)));
        float q1 = phi_f(bf2f((unsigned short)(qp >> 16)));
        float k0 = phi_f(bf2f((unsigned short)(kp & 0xffff)));
        float k1 = phi_f(bf2f((unsigned short)(kp >> 16)));
        float v0 = bf2f((unsigned short)(vp & 0xffff));
        float v1 = bf2f((unsigned short)(vp >> 16));
        skv0 = fmaf(dec, skv0, k0 * v0);
        skv1 = fmaf(dec, skv1, k1 * v1);
        sk0  = fmaf(dec, sk0,  k0);
        sk1  = fmaf(dec, sk1,  k1);
        float den = fmaf(q0, sk0, q1 * sk1);
        #pragma unroll
        for (int m = 1; m < 64; m <<= 1) den += __shfl_xor(den, m, 64);
        den = fmaxf(den, 1e-6f);
        float inv = 1.f / den;
        unsigned o = ((unsigned)f2bf(q1 * skv1 * inv) << 16) |
                     (unsigned)f2bf(q0 * skv0 * inv);
        *reinterpret_cast<unsigned*>(abase + (size_t)t * HID + 2 * lane) = o;
    }
}

// ---------------- launch ----------------
extern "C" void kernel_launch(void* const* d_in, const int* in_sizes, int n_in,
                              void* d_out, int out_size, void* d_ws, size_t ws_size,
                              hipStream_t stream) {
    const float* x      = (const float*)d_in[0];   // [2,4096,2048]
    const float* w_qkv  = (const float*)d_in[1];   // [2048,6144]
    const float* w_out  = (const float*)d_in[2];   // [2048,2048]
    const float* decayp = (const float*)d_in[3];   // [16]
    float* out = (float*)d_out;

    // workspace layout
    char* ws = (char*)d_ws;
    unsigned short* xb     = (unsigned short*)ws;                         // 8192*2048
    unsigned short* wqkvT  = xb    + (size_t)ROWS * HID;                  // 6144*2048
    unsigned short* woutT  = wqkvT + (size_t)QKV_N * HID;                 // 2048*2048
    unsigned short* qkvb   = woutT + (size_t)HID * HID;                   // 8192*6144
    unsigned short* attnb  = qkvb  + (size_t)ROWS * QKV_N;                // 8192*2048
    float* fkv = (float*)(attnb + (size_t)ROWS * HID);
    float* fk  = fkv + (size_t)NB * NH * NCH * ND;
    float* ckv = fk  + (size_t)NB * NH * NCH * ND;
    float* ck  = ckv + (size_t)NB * NH * NCH * ND;

    // fused prep: cast x + transpose both weights (1 launch)
    prep_kernel<<<PREP_CAST_BLK + PREP_TQ_BLK + PREP_TW_BLK, 256, 0, stream>>>(
        x, w_qkv, w_out, xb, wqkvT, woutT);

    // GEMM1: qkvb = xb @ wqkvT^T   (bf16 out)  grid 64x48 = 3072 blocks
    {
        int nby = ROWS / 128, nbx = QKV_N / 128;
        gemm128<unsigned short><<<nby * nbx, 256, 0, stream>>>(
            xb, wqkvT, qkvb, ROWS, QKV_N, HID, nby / 8);
    }

    // chunked decay scans
    scan_pass1<<<NB * NH * NCH, 64, 0, stream>>>(qkvb, decayp, fkv, fk);
    scan_pass2<<<NB * NH, 64, 0, stream>>>(fkv, fk, decayp, ckv, ck,
                                           out + (size_t)ROWS * HID);
    scan_pass3<<<NB * NH * NCH, 64, 0, stream>>>(qkvb, decayp, ckv, ck, attnb);

    // GEMM2: out = attnb @ woutT^T  (f32 out)  grid 64x16 = 1024 blocks
    {
        int nby = ROWS / 128, nbx = HID / 128;
        gemm128<float><<<nby * nbx, 256, 0, stream>>>(
            attnb, woutT, out, ROWS, HID, HID, nby / 8);
    }
}

// Round 14
// 347.003 us; speedup vs baseline: 2.8974x; 2.8974x over previous
//
#include <hip/hip_runtime.h>
#include <hip/hip_bf16.h>
#include <stdint.h>

// Problem constants
constexpr int NB = 2;        // batch
constexpr int NT = 4096;     // seq len
constexpr int NH = 16;       // heads
constexpr int ND = 128;      // head dim
constexpr int HID = NH * ND;         // 2048
constexpr int QKV_N = 3 * HID;       // 6144
constexpr int ROWS = NB * NT;        // 8192
constexpr int CHUNK = 64;            // scan chunk length
constexpr int NCH = NT / CHUNK;      // 64 chunks

typedef __bf16 bf16x8 __attribute__((ext_vector_type(8)));
typedef float  f32x4  __attribute__((ext_vector_type(4)));

__device__ inline unsigned short f2bf(float f) {       // RNE fp32->bf16
    unsigned u = __builtin_bit_cast(unsigned, f);
    u += 0x7fffu + ((u >> 16) & 1u);
    return (unsigned short)(u >> 16);
}
__device__ inline float bf2f(unsigned short b) {
    unsigned u = ((unsigned)b) << 16;
    return __builtin_bit_cast(float, u);
}

// ---------- fused prep: cast x AND transpose both weights (1 launch) ------
constexpr int PREP_CAST_BLK = 2048;
constexpr int PREP_TQ_BLK   = (QKV_N / 32) * (HID / 32);   // 12288
constexpr int PREP_TW_BLK   = (HID / 32) * (HID / 32);     // 4096

__global__ __launch_bounds__(256) void prep_kernel(
        const float* __restrict__ x, const float* __restrict__ w_qkv,
        const float* __restrict__ w_out,
        unsigned short* __restrict__ xb, unsigned short* __restrict__ wqkvT,
        unsigned short* __restrict__ woutT) {
    __shared__ float tile[32][33];
    const int b = blockIdx.x;
    if (b < PREP_CAST_BLK) {
        size_t n4 = (size_t)ROWS * HID / 4;
        size_t i = b * (size_t)blockDim.x + threadIdx.x;
        size_t stride = (size_t)PREP_CAST_BLK * blockDim.x;
        for (; i < n4; i += stride) {
            float4 v = reinterpret_cast<const float4*>(x)[i];
            ushort4 o;
            o.x = f2bf(v.x); o.y = f2bf(v.y); o.z = f2bf(v.z); o.w = f2bf(v.w);
            reinterpret_cast<ushort4*>(xb)[i] = o;
        }
        return;
    }
    const float* in;
    unsigned short* out;
    int R, Cn, tb;
    if (b < PREP_CAST_BLK + PREP_TQ_BLK) {
        tb = b - PREP_CAST_BLK; in = w_qkv; out = wqkvT; R = HID; Cn = QKV_N;
    } else {
        tb = b - PREP_CAST_BLK - PREP_TQ_BLK; in = w_out; out = woutT; R = HID; Cn = HID;
    }
    const int nbx = Cn / 32;
    const int c0 = (tb % nbx) * 32, r0 = (tb / nbx) * 32;
    const int c  = threadIdx.x & 31;
    const int r8 = threadIdx.x >> 5;          // 0..7
    #pragma unroll
    for (int i = 0; i < 32; i += 8)
        tile[r8 + i][c] = in[(size_t)(r0 + r8 + i) * Cn + c0 + c];
    __syncthreads();
    #pragma unroll
    for (int i = 0; i < 32; i += 8)
        out[(size_t)(c0 + r8 + i) * R + r0 + c] = f2bf(tile[c][r8 + i]);
}

// ====== 128x128 4-wave BK=64 double-buffered GEMM, 2 blocks/CU =============
// Round 14: revert to the round-10 GEMM verbatim (best verified: 192 µs,
// MfmaUtil 52%, FETCH 197 MB). XCD 2D-window mapping + 2 barrier domains.
// r13's B-direct experiment falsified (uncoalesced + unprefetched);
// LDS-BW remains the structural limiter of this tile shape.

__device__ __forceinline__ void gll(const unsigned short* src, unsigned short* dst) {
    __builtin_amdgcn_global_load_lds(
        (const __attribute__((address_space(1))) void*)src,
        (__attribute__((address_space(3))) void*)dst, 16, 0, 0);
}

// Stage one 128x64 bf16 tile (16 KB): 4 waves x 4 rounds x 8 rows.
__device__ __forceinline__ void stage_t(const unsigned short* G, int K, int k0,
                                        unsigned short* lds, int wid, int lane) {
    const int rbase = wid * 32;
    const int rl = lane >> 3;                        // 0..7 row within group
    const int ce = ((lane & 7) ^ rl) * 8;            // inverse-swizzled col
    #pragma unroll
    for (int j = 0; j < 4; ++j) {
        gll(G + (size_t)(rbase + j * 8 + rl) * K + k0 + ce,
            lds + (rbase + j * 8) * 64);
    }
}

// swizzled ds_read: row r, k-slot kk*4+fq (8 slots of 8 bf16 across BK=64)
__device__ __forceinline__ bf16x8 ld_frag(const unsigned short* tile,
                                          int r, int kk, int fq) {
    int slot = (kk * 4 + fq) ^ (r & 7);
    return *reinterpret_cast<const bf16x8*>(tile + r * 64 + slot * 8);
}

template <typename OUT_T>
__global__ __launch_bounds__(256, 2) void gemm128(
        const unsigned short* __restrict__ A,   // [M][K] bf16
        const unsigned short* __restrict__ Bt,  // [N][K] bf16
        OUT_T* __restrict__ C,                  // [M][N]
        int M, int N, int K, int byc) {
    __shared__ unsigned short As0[128 * 64];
    __shared__ unsigned short As1[128 * 64];
    __shared__ unsigned short Bs0[128 * 64];
    __shared__ unsigned short Bs1[128 * 64];

    const int bid = blockIdx.x;
    const int xcd = bid & 7;
    const int c   = bid >> 3;
    const int by  = xcd * byc + (c % byc);   // 8-wide by-band per XCD
    const int bx  = c / byc;                 // column-major within band
    const int tid = threadIdx.x, wid = tid >> 6, lane = tid & 63;
    const int wm  = wid >> 1, wn = wid & 1;         // 2x2 waves, 64x64 each
    const int fr  = lane & 15, fq = lane >> 4;

    const unsigned short* Ag = A  + (size_t)by * 128 * K;
    const unsigned short* Bg = Bt + (size_t)bx * 128 * K;

    f32x4 acc[4][4] = {};

    stage_t(Ag, K, 0, As0, wid, lane);
    stage_t(Bg, K, 0, Bs0, wid, lane);
    __syncthreads();

    const int NK = K / 64;
    for (int t = 0; t < NK; ++t) {
        const unsigned short* Ac = (t & 1) ? As1 : As0;
        const unsigned short* Bc = (t & 1) ? Bs1 : Bs0;
        if (t + 1 < NK) {   // prefetch next K-tile into the other buffer
            unsigned short* An = (t & 1) ? As0 : As1;
            unsigned short* Bn = (t & 1) ? Bs0 : Bs1;
            stage_t(Ag, K, (t + 1) * 64, An, wid, lane);
            stage_t(Bg, K, (t + 1) * 64, Bn, wid, lane);
        }
        bf16x8 af[4][2], bf[4][2];
        #pragma unroll
        for (int m = 0; m < 4; ++m) {
            int r = wm * 64 + m * 16 + fr;
            af[m][0] = ld_frag(Ac, r, 0, fq);
            af[m][1] = ld_frag(Ac, r, 1, fq);
        }
        #pragma unroll
        for (int n = 0; n < 4; ++n) {
            int r = wn * 64 + n * 16 + fr;
            bf[n][0] = ld_frag(Bc, r, 0, fq);
            bf[n][1] = ld_frag(Bc, r, 1, fq);
        }
        __builtin_amdgcn_s_setprio(1);
        #pragma unroll
        for (int kk = 0; kk < 2; ++kk)
            #pragma unroll
            for (int m = 0; m < 4; ++m)
                #pragma unroll
                for (int n = 0; n < 4; ++n)
                    acc[m][n] = __builtin_amdgcn_mfma_f32_16x16x32_bf16(
                        af[m][kk], bf[n][kk], acc[m][n], 0, 0, 0);
        __builtin_amdgcn_s_setprio(0);
        __syncthreads();
    }

    // C write (verified C/D layout: row = fq*4+r, col = fr)
    const int bm = by * 128, bn = bx * 128;
    #pragma unroll
    for (int m = 0; m < 4; ++m) {
        #pragma unroll
        for (int n = 0; n < 4; ++n) {
            #pragma unroll
            for (int r = 0; r < 4; ++r) {
                int row = bm + wm * 64 + m * 16 + fq * 4 + r;
                int col = bn + wn * 64 + n * 16 + fr;
                float v = acc[m][n][r];
                if constexpr (sizeof(OUT_T) == 2)
                    C[(size_t)row * N + col] = (OUT_T)f2bf(v);
                else
                    C[(size_t)row * N + col] = (OUT_T)v;
            }
        }
    }
}

// ---------------- scan helpers ----------------
__device__ inline float phi_f(float z) { return z > 0.f ? z + 1.f : __expf(z); }
__device__ inline float sigmoid_f(float z) { return 1.f / (1.f + __expf(-z)); }

// Pass 1: per-(b,h,chunk) local scan finals (zero init). qkv bf16.
__global__ void scan_pass1(const unsigned short* __restrict__ qkv,
                           const float* __restrict__ decay_param,
                           float* __restrict__ fkv, float* __restrict__ fk) {
    const int blk = blockIdx.x;
    const int c = blk % NCH;
    const int h = (blk / NCH) % NH;
    const int b = blk / (NCH * NH);
    const int lane = threadIdx.x;
    const float dec = sigmoid_f(decay_param[h]);

    float skv0 = 0.f, skv1 = 0.f, sk0 = 0.f, sk1 = 0.f;
    const unsigned short* base =
        qkv + ((size_t)b * NT + (size_t)c * CHUNK) * QKV_N + h * ND;
    for (int t = 0; t < CHUNK; ++t) {
        const unsigned short* r = base + (size_t)t * QKV_N;
        unsigned kp = *reinterpret_cast<const unsigned*>(r + HID + 2 * lane);
        unsigned vp = *reinterpret_cast<const unsigned*>(r + 2 * HID + 2 * lane);
        float k0 = phi_f(bf2f((unsigned short)(kp & 0xffff)));
        float k1 = phi_f(bf2f((unsigned short)(kp >> 16)));
        float v0 = bf2f((unsigned short)(vp & 0xffff));
        float v1 = bf2f((unsigned short)(vp >> 16));
        skv0 = fmaf(dec, skv0, k0 * v0);
        skv1 = fmaf(dec, skv1, k1 * v1);
        sk0  = fmaf(dec, sk0,  k0);
        sk1  = fmaf(dec, sk1,  k1);
    }
    size_t o = (size_t)blk * ND + 2 * lane;
    *reinterpret_cast<float2*>(&fkv[o]) = make_float2(skv0, skv1);
    *reinterpret_cast<float2*>(&fk[o])  = make_float2(sk0, sk1);
}

// Pass 2: sequential chunk combine; emits carry-ins and final states.
__global__ void scan_pass2(const float* __restrict__ fkv, const float* __restrict__ fk,
                           const float* __restrict__ decay_param,
                           float* __restrict__ ckv, float* __restrict__ ck,
                           float* __restrict__ out_states) {
    const int bh = blockIdx.x;
    const int h = bh % NH;
    const int lane = threadIdx.x;
    const float dec = sigmoid_f(decay_param[h]);
    const float dL = powf(dec, (float)CHUNK);

    float Skv0 = 0.f, Skv1 = 0.f, Sk0 = 0.f, Sk1 = 0.f;
    for (int c = 0; c < NCH; ++c) {
        size_t o = ((size_t)bh * NCH + c) * ND + 2 * lane;
        *reinterpret_cast<float2*>(&ckv[o]) = make_float2(Skv0, Skv1);
        *reinterpret_cast<float2*>(&ck[o])  = make_float2(Sk0, Sk1);
        float2 fv = *reinterpret_cast<const float2*>(&fkv[o]);
        float2 fs = *reinterpret_cast<const float2*>(&fk[o]);
        Skv0 = fmaf(dL, Skv0, fv.x);
        Skv1 = fmaf(dL, Skv1, fv.y);
        Sk0  = fmaf(dL, Sk0,  fs.x);
        Sk1  = fmaf(dL, Sk1,  fs.y);
    }
    size_t so = (size_t)bh * ND + 2 * lane;
    *reinterpret_cast<float2*>(&out_states[so]) = make_float2(Skv0, Skv1);
    *reinterpret_cast<float2*>(&out_states[NB * NH * ND + so]) = make_float2(Sk0, Sk1);
}

// Pass 3: replay with carry-in; writes attn in bf16.
__global__ void scan_pass3(const unsigned short* __restrict__ qkv,
                           const float* __restrict__ decay_param,
                           const float* __restrict__ ckv, const float* __restrict__ ck,
                           unsigned short* __restrict__ attn) {
    const int blk = blockIdx.x;
    const int c = blk % NCH;
    const int h = (blk / NCH) % NH;
    const int b = blk / (NCH * NH);
    const int lane = threadIdx.x;
    const float dec = sigmoid_f(decay_param[h]);

    size_t co = (size_t)blk * ND + 2 * lane;
    float2 cv = *reinterpret_cast<const float2*>(&ckv[co]);
    float2 cs = *reinterpret_cast<const float2*>(&ck[co]);
    float skv0 = cv.x, skv1 = cv.y, sk0 = cs.x, sk1 = cs.y;

    const unsigned short* base =
        qkv + ((size_t)b * NT + (size_t)c * CHUNK) * QKV_N + h * ND;
    unsigned short* abase =
        attn + ((size_t)b * NT + (size_t)c * CHUNK) * HID + h * ND;

    for (int t = 0; t < CHUNK; ++t) {
        const unsigned short* r = base + (size_t)t * QKV_N;
        unsigned qp = *reinterpret_cast<const unsigned*>(r + 2 * lane);
        unsigned kp = *reinterpret_cast<const unsigned*>(r + HID + 2 * lane);
        unsigned vp = *reinterpret_cast<const unsigned*>(r + 2 * HID + 2 * lane);
        float q0 = phi_f(bf2f((unsigned short)(qp & 0xffff)));
        float q1 = phi_f(bf2f((unsigned short)(qp >> 16)));
        float k0 = phi_f(bf2f((unsigned short)(kp & 0xffff)));
        float k1 = phi_f(bf2f((unsigned short)(kp >> 16)));
        float v0 = bf2f((unsigned short)(vp & 0xffff));
        float v1 = bf2f((unsigned short)(vp >> 16));
        skv0 = fmaf(dec, skv0, k0 * v0);
        skv1 = fmaf(dec, skv1, k1 * v1);
        sk0  = fmaf(dec, sk0,  k0);
        sk1  = fmaf(dec, sk1,  k1);
        float den = fmaf(q0, sk0, q1 * sk1);
        #pragma unroll
        for (int m = 1; m < 64; m <<= 1) den += __shfl_xor(den, m, 64);
        den = fmaxf(den, 1e-6f);
        float inv = 1.f / den;
        unsigned o = ((unsigned)f2bf(q1 * skv1 * inv) << 16) |
                     (unsigned)f2bf(q0 * skv0 * inv);
        *reinterpret_cast<unsigned*>(abase + (size_t)t * HID + 2 * lane) = o;
    }
}

// ---------------- launch ----------------
extern "C" void kernel_launch(void* const* d_in, const int* in_sizes, int n_in,
                              void* d_out, int out_size, void* d_ws, size_t ws_size,
                              hipStream_t stream) {
    const float* x      = (const float*)d_in[0];   // [2,4096,2048]
    const float* w_qkv  = (const float*)d_in[1];   // [2048,6144]
    const float* w_out  = (const float*)d_in[2];   // [2048,2048]
    const float* decayp = (const float*)d_in[3];   // [16]
    float* out = (float*)d_out;

    // workspace layout
    char* ws = (char*)d_ws;
    unsigned short* xb     = (unsigned short*)ws;                         // 8192*2048
    unsigned short* wqkvT  = xb    + (size_t)ROWS * HID;                  // 6144*2048
    unsigned short* woutT  = wqkvT + (size_t)QKV_N * HID;                 // 2048*2048
    unsigned short* qkvb   = woutT + (size_t)HID * HID;                   // 8192*6144
    unsigned short* attnb  = qkvb  + (size_t)ROWS * QKV_N;                // 8192*2048
    float* fkv = (float*)(attnb + (size_t)ROWS * HID);
    float* fk  = fkv + (size_t)NB * NH * NCH * ND;
    float* ckv = fk  + (size_t)NB * NH * NCH * ND;
    float* ck  = ckv + (size_t)NB * NH * NCH * ND;

    // fused prep: cast x + transpose both weights (1 launch)
    prep_kernel<<<PREP_CAST_BLK + PREP_TQ_BLK + PREP_TW_BLK, 256, 0, stream>>>(
        x, w_qkv, w_out, xb, wqkvT, woutT);

    // GEMM1: qkvb = xb @ wqkvT^T   (bf16 out)  grid 64x48 = 3072 blocks
    {
        int nby = ROWS / 128, nbx = QKV_N / 128;
        gemm128<unsigned short><<<nby * nbx, 256, 0, stream>>>(
            xb, wqkvT, qkvb, ROWS, QKV_N, HID, nby / 8);
    }

    // chunked decay scans
    scan_pass1<<<NB * NH * NCH, 64, 0, stream>>>(qkvb, decayp, fkv, fk);
    scan_pass2<<<NB * NH, 64, 0, stream>>>(fkv, fk, decayp, ckv, ck,
                                           out + (size_t)ROWS * HID);
    scan_pass3<<<NB * NH * NCH, 64, 0, stream>>>(qkvb, decayp, ckv, ck, attnb);

    // GEMM2: out = attnb @ woutT^T  (f32 out)  grid 64x16 = 1024 blocks
    {
        int nby = ROWS / 128, nbx = HID / 128;
        gemm128<float><<<nby * nbx, 256, 0, stream>>>(
            attnb, woutT, out, ROWS, HID, HID, nby / 8);
    }
}

// Round 15
// 332.038 us; speedup vs baseline: 3.0280x; 1.0451x over previous
//
#include <hip/hip_runtime.h>
#include <hip/hip_bf16.h>
#include <stdint.h>

// Problem constants
constexpr int NB = 2;        // batch
constexpr int NT = 4096;     // seq len
constexpr int NH = 16;       // heads
constexpr int ND = 128;      // head dim
constexpr int HID = NH * ND;         // 2048
constexpr int QKV_N = 3 * HID;       // 6144
constexpr int ROWS = NB * NT;        // 8192
constexpr int CHUNK = 32;            // scan chunk length (r15: 64->32, 2x TLP)
constexpr int NCH = NT / CHUNK;      // 128 chunks

typedef __bf16 bf16x8 __attribute__((ext_vector_type(8)));
typedef float  f32x4  __attribute__((ext_vector_type(4)));

__device__ inline unsigned short f2bf(float f) {       // RNE fp32->bf16
    unsigned u = __builtin_bit_cast(unsigned, f);
    u += 0x7fffu + ((u >> 16) & 1u);
    return (unsigned short)(u >> 16);
}
__device__ inline float bf2f(unsigned short b) {
    unsigned u = ((unsigned)b) << 16;
    return __builtin_bit_cast(float, u);
}

// ---------- fused prep: cast x AND transpose both weights (1 launch) ------
constexpr int PREP_CAST_BLK = 2048;
constexpr int PREP_TQ_BLK   = (QKV_N / 32) * (HID / 32);   // 12288
constexpr int PREP_TW_BLK   = (HID / 32) * (HID / 32);     // 4096

__global__ __launch_bounds__(256) void prep_kernel(
        const float* __restrict__ x, const float* __restrict__ w_qkv,
        const float* __restrict__ w_out,
        unsigned short* __restrict__ xb, unsigned short* __restrict__ wqkvT,
        unsigned short* __restrict__ woutT) {
    __shared__ float tile[32][33];
    const int b = blockIdx.x;
    if (b < PREP_CAST_BLK) {
        size_t n4 = (size_t)ROWS * HID / 4;
        size_t i = b * (size_t)blockDim.x + threadIdx.x;
        size_t stride = (size_t)PREP_CAST_BLK * blockDim.x;
        for (; i < n4; i += stride) {
            float4 v = reinterpret_cast<const float4*>(x)[i];
            ushort4 o;
            o.x = f2bf(v.x); o.y = f2bf(v.y); o.z = f2bf(v.z); o.w = f2bf(v.w);
            reinterpret_cast<ushort4*>(xb)[i] = o;
        }
        return;
    }
    const float* in;
    unsigned short* out;
    int R, Cn, tb;
    if (b < PREP_CAST_BLK + PREP_TQ_BLK) {
        tb = b - PREP_CAST_BLK; in = w_qkv; out = wqkvT; R = HID; Cn = QKV_N;
    } else {
        tb = b - PREP_CAST_BLK - PREP_TQ_BLK; in = w_out; out = woutT; R = HID; Cn = HID;
    }
    const int nbx = Cn / 32;
    const int c0 = (tb % nbx) * 32, r0 = (tb / nbx) * 32;
    const int c  = threadIdx.x & 31;
    const int r8 = threadIdx.x >> 5;          // 0..7
    #pragma unroll
    for (int i = 0; i < 32; i += 8)
        tile[r8 + i][c] = in[(size_t)(r0 + r8 + i) * Cn + c0 + c];
    __syncthreads();
    #pragma unroll
    for (int i = 0; i < 32; i += 8)
        out[(size_t)(c0 + r8 + i) * R + r0 + c] = f2bf(tile[c][r8 + i]);
}

// ====== 128x128 4-wave BK=64 double-buffered GEMM, 2 blocks/CU =============
// Best verified config (r10/r14): 192 µs GEMM1, MfmaUtil 52%, FETCH 197 MB.
// XCD 2D-window mapping + 2 barrier domains. LDS-BW is the structural
// limiter of this tile shape (96 KB LDS traffic vs 308 cy MFMA per K-step).

__device__ __forceinline__ void gll(const unsigned short* src, unsigned short* dst) {
    __builtin_amdgcn_global_load_lds(
        (const __attribute__((address_space(1))) void*)src,
        (__attribute__((address_space(3))) void*)dst, 16, 0, 0);
}

// Stage one 128x64 bf16 tile (16 KB): 4 waves x 4 rounds x 8 rows.
__device__ __forceinline__ void stage_t(const unsigned short* G, int K, int k0,
                                        unsigned short* lds, int wid, int lane) {
    const int rbase = wid * 32;
    const int rl = lane >> 3;                        // 0..7 row within group
    const int ce = ((lane & 7) ^ rl) * 8;            // inverse-swizzled col
    #pragma unroll
    for (int j = 0; j < 4; ++j) {
        gll(G + (size_t)(rbase + j * 8 + rl) * K + k0 + ce,
            lds + (rbase + j * 8) * 64);
    }
}

// swizzled ds_read: row r, k-slot kk*4+fq (8 slots of 8 bf16 across BK=64)
__device__ __forceinline__ bf16x8 ld_frag(const unsigned short* tile,
                                          int r, int kk, int fq) {
    int slot = (kk * 4 + fq) ^ (r & 7);
    return *reinterpret_cast<const bf16x8*>(tile + r * 64 + slot * 8);
}

template <typename OUT_T>
__global__ __launch_bounds__(256, 2) void gemm128(
        const unsigned short* __restrict__ A,   // [M][K] bf16
        const unsigned short* __restrict__ Bt,  // [N][K] bf16
        OUT_T* __restrict__ C,                  // [M][N]
        int M, int N, int K, int byc) {
    __shared__ unsigned short As0[128 * 64];
    __shared__ unsigned short As1[128 * 64];
    __shared__ unsigned short Bs0[128 * 64];
    __shared__ unsigned short Bs1[128 * 64];

    const int bid = blockIdx.x;
    const int xcd = bid & 7;
    const int c   = bid >> 3;
    const int by  = xcd * byc + (c % byc);   // 8-wide by-band per XCD
    const int bx  = c / byc;                 // column-major within band
    const int tid = threadIdx.x, wid = tid >> 6, lane = tid & 63;
    const int wm  = wid >> 1, wn = wid & 1;         // 2x2 waves, 64x64 each
    const int fr  = lane & 15, fq = lane >> 4;

    const unsigned short* Ag = A  + (size_t)by * 128 * K;
    const unsigned short* Bg = Bt + (size_t)bx * 128 * K;

    f32x4 acc[4][4] = {};

    stage_t(Ag, K, 0, As0, wid, lane);
    stage_t(Bg, K, 0, Bs0, wid, lane);
    __syncthreads();

    const int NK = K / 64;
    for (int t = 0; t < NK; ++t) {
        const unsigned short* Ac = (t & 1) ? As1 : As0;
        const unsigned short* Bc = (t & 1) ? Bs1 : Bs0;
        if (t + 1 < NK) {   // prefetch next K-tile into the other buffer
            unsigned short* An = (t & 1) ? As0 : As1;
            unsigned short* Bn = (t & 1) ? Bs0 : Bs1;
            stage_t(Ag, K, (t + 1) * 64, An, wid, lane);
            stage_t(Bg, K, (t + 1) * 64, Bn, wid, lane);
        }
        bf16x8 af[4][2], bf[4][2];
        #pragma unroll
        for (int m = 0; m < 4; ++m) {
            int r = wm * 64 + m * 16 + fr;
            af[m][0] = ld_frag(Ac, r, 0, fq);
            af[m][1] = ld_frag(Ac, r, 1, fq);
        }
        #pragma unroll
        for (int n = 0; n < 4; ++n) {
            int r = wn * 64 + n * 16 + fr;
            bf[n][0] = ld_frag(Bc, r, 0, fq);
            bf[n][1] = ld_frag(Bc, r, 1, fq);
        }
        __builtin_amdgcn_s_setprio(1);
        #pragma unroll
        for (int kk = 0; kk < 2; ++kk)
            #pragma unroll
            for (int m = 0; m < 4; ++m)
                #pragma unroll
                for (int n = 0; n < 4; ++n)
                    acc[m][n] = __builtin_amdgcn_mfma_f32_16x16x32_bf16(
                        af[m][kk], bf[n][kk], acc[m][n], 0, 0, 0);
        __builtin_amdgcn_s_setprio(0);
        __syncthreads();
    }

    // C write (verified C/D layout: row = fq*4+r, col = fr)
    const int bm = by * 128, bn = bx * 128;
    #pragma unroll
    for (int m = 0; m < 4; ++m) {
        #pragma unroll
        for (int n = 0; n < 4; ++n) {
            #pragma unroll
            for (int r = 0; r < 4; ++r) {
                int row = bm + wm * 64 + m * 16 + fq * 4 + r;
                int col = bn + wn * 64 + n * 16 + fr;
                float v = acc[m][n][r];
                if constexpr (sizeof(OUT_T) == 2)
                    C[(size_t)row * N + col] = (OUT_T)f2bf(v);
                else
                    C[(size_t)row * N + col] = (OUT_T)v;
            }
        }
    }
}

// ---------------- scan helpers ----------------
__device__ inline float phi_f(float z) { return z > 0.f ? z + 1.f : __expf(z); }
__device__ inline float sigmoid_f(float z) { return 1.f / (1.f + __expf(-z)); }

// Pass 1: per-(b,h,chunk) local scan finals (zero init). qkv bf16.
// r15: CHUNK=32 -> 4096 blocks (16 waves/CU) to hide load latency.
__global__ void scan_pass1(const unsigned short* __restrict__ qkv,
                           const float* __restrict__ decay_param,
                           float* __restrict__ fkv, float* __restrict__ fk) {
    const int blk = blockIdx.x;
    const int c = blk % NCH;
    const int h = (blk / NCH) % NH;
    const int b = blk / (NCH * NH);
    const int lane = threadIdx.x;
    const float dec = sigmoid_f(decay_param[h]);

    float skv0 = 0.f, skv1 = 0.f, sk0 = 0.f, sk1 = 0.f;
    const unsigned short* base =
        qkv + ((size_t)b * NT + (size_t)c * CHUNK) * QKV_N + h * ND;
    for (int t = 0; t < CHUNK; ++t) {
        const unsigned short* r = base + (size_t)t * QKV_N;
        unsigned kp = *reinterpret_cast<const unsigned*>(r + HID + 2 * lane);
        unsigned vp = *reinterpret_cast<const unsigned*>(r + 2 * HID + 2 * lane);
        float k0 = phi_f(bf2f((unsigned short)(kp & 0xffff)));
        float k1 = phi_f(bf2f((unsigned short)(kp >> 16)));
        float v0 = bf2f((unsigned short)(vp & 0xffff));
        float v1 = bf2f((unsigned short)(vp >> 16));
        skv0 = fmaf(dec, skv0, k0 * v0);
        skv1 = fmaf(dec, skv1, k1 * v1);
        sk0  = fmaf(dec, sk0,  k0);
        sk1  = fmaf(dec, sk1,  k1);
    }
    size_t o = (size_t)blk * ND + 2 * lane;
    *reinterpret_cast<float2*>(&fkv[o]) = make_float2(skv0, skv1);
    *reinterpret_cast<float2*>(&fk[o])  = make_float2(sk0, sk1);
}

// Pass 2: sequential chunk combine; emits carry-ins and final states.
__global__ void scan_pass2(const float* __restrict__ fkv, const float* __restrict__ fk,
                           const float* __restrict__ decay_param,
                           float* __restrict__ ckv, float* __restrict__ ck,
                           float* __restrict__ out_states) {
    const int bh = blockIdx.x;
    const int h = bh % NH;
    const int lane = threadIdx.x;
    const float dec = sigmoid_f(decay_param[h]);
    const float dL = powf(dec, (float)CHUNK);

    float Skv0 = 0.f, Skv1 = 0.f, Sk0 = 0.f, Sk1 = 0.f;
    for (int c = 0; c < NCH; ++c) {
        size_t o = ((size_t)bh * NCH + c) * ND + 2 * lane;
        *reinterpret_cast<float2*>(&ckv[o]) = make_float2(Skv0, Skv1);
        *reinterpret_cast<float2*>(&ck[o])  = make_float2(Sk0, Sk1);
        float2 fv = *reinterpret_cast<const float2*>(&fkv[o]);
        float2 fs = *reinterpret_cast<const float2*>(&fk[o]);
        Skv0 = fmaf(dL, Skv0, fv.x);
        Skv1 = fmaf(dL, Skv1, fv.y);
        Sk0  = fmaf(dL, Sk0,  fs.x);
        Sk1  = fmaf(dL, Sk1,  fs.y);
    }
    size_t so = (size_t)bh * ND + 2 * lane;
    *reinterpret_cast<float2*>(&out_states[so]) = make_float2(Skv0, Skv1);
    *reinterpret_cast<float2*>(&out_states[NB * NH * ND + so]) = make_float2(Sk0, Sk1);
}

// Pass 3: replay with carry-in; writes attn in bf16.
__global__ void scan_pass3(const unsigned short* __restrict__ qkv,
                           const float* __restrict__ decay_param,
                           const float* __restrict__ ckv, const float* __restrict__ ck,
                           unsigned short* __restrict__ attn) {
    const int blk = blockIdx.x;
    const int c = blk % NCH;
    const int h = (blk / NCH) % NH;
    const int b = blk / (NCH * NH);
    const int lane = threadIdx.x;
    const float dec = sigmoid_f(decay_param[h]);

    size_t co = (size_t)blk * ND + 2 * lane;
    float2 cv = *reinterpret_cast<const float2*>(&ckv[co]);
    float2 cs = *reinterpret_cast<const float2*>(&ck[co]);
    float skv0 = cv.x, skv1 = cv.y, sk0 = cs.x, sk1 = cs.y;

    const unsigned short* base =
        qkv + ((size_t)b * NT + (size_t)c * CHUNK) * QKV_N + h * ND;
    unsigned short* abase =
        attn + ((size_t)b * NT + (size_t)c * CHUNK) * HID + h * ND;

    for (int t = 0; t < CHUNK; ++t) {
        const unsigned short* r = base + (size_t)t * QKV_N;
        unsigned qp = *reinterpret_cast<const unsigned*>(r + 2 * lane);
        unsigned kp = *reinterpret_cast<const unsigned*>(r + HID + 2 * lane);
        unsigned vp = *reinterpret_cast<const unsigned*>(r + 2 * HID + 2 * lane);
        float q0 = phi_f(bf2f((unsigned short)(qp & 0xffff)));
        float q1 = phi_f(bf2f((unsigned short)(qp >> 16)));
        float k0 = phi_f(bf2f((unsigned short)(kp & 0xffff)));
        float k1 = phi_f(bf2f((unsigned short)(kp >> 16)));
        float v0 = bf2f((unsigned short)(vp & 0xffff));
        float v1 = bf2f((unsigned short)(vp >> 16));
        skv0 = fmaf(dec, skv0, k0 * v0);
        skv1 = fmaf(dec, skv1, k1 * v1);
        sk0  = fmaf(dec, sk0,  k0);
        sk1  = fmaf(dec, sk1,  k1);
        float den = fmaf(q0, sk0, q1 * sk1);
        #pragma unroll
        for (int m = 1; m < 64; m <<= 1) den += __shfl_xor(den, m, 64);
        den = fmaxf(den, 1e-6f);
        float inv = 1.f / den;
        unsigned o = ((unsigned)f2bf(q1 * skv1 * inv) << 16) |
                     (unsigned)f2bf(q0 * skv0 * inv);
        *reinterpret_cast<unsigned*>(abase + (size_t)t * HID + 2 * lane) = o;
    }
}

// ---------------- launch ----------------
extern "C" void kernel_launch(void* const* d_in, const int* in_sizes, int n_in,
                              void* d_out, int out_size, void* d_ws, size_t ws_size,
                              hipStream_t stream) {
    const float* x      = (const float*)d_in[0];   // [2,4096,2048]
    const float* w_qkv  = (const float*)d_in[1];   // [2048,6144]
    const float* w_out  = (const float*)d_in[2];   // [2048,2048]
    const float* decayp = (const float*)d_in[3];   // [16]
    float* out = (float*)d_out;

    // workspace layout
    char* ws = (char*)d_ws;
    unsigned short* xb     = (unsigned short*)ws;                         // 8192*2048
    unsigned short* wqkvT  = xb    + (size_t)ROWS * HID;                  // 6144*2048
    unsigned short* woutT  = wqkvT + (size_t)QKV_N * HID;                 // 2048*2048
    unsigned short* qkvb   = woutT + (size_t)HID * HID;                   // 8192*6144
    unsigned short* attnb  = qkvb  + (size_t)ROWS * QKV_N;                // 8192*2048
    float* fkv = (float*)(attnb + (size_t)ROWS * HID);
    float* fk  = fkv + (size_t)NB * NH * NCH * ND;
    float* ckv = fk  + (size_t)NB * NH * NCH * ND;
    float* ck  = ckv + (size_t)NB * NH * NCH * ND;

    // fused prep: cast x + transpose both weights (1 launch)
    prep_kernel<<<PREP_CAST_BLK + PREP_TQ_BLK + PREP_TW_BLK, 256, 0, stream>>>(
        x, w_qkv, w_out, xb, wqkvT, woutT);

    // GEMM1: qkvb = xb @ wqkvT^T   (bf16 out)  grid 64x48 = 3072 blocks
    {
        int nby = ROWS / 128, nbx = QKV_N / 128;
        gemm128<unsigned short><<<nby * nbx, 256, 0, stream>>>(
            xb, wqkvT, qkvb, ROWS, QKV_N, HID, nby / 8);
    }

    // chunked decay scans (CHUNK=32 -> 4096 blocks, 2x TLP vs r14)
    scan_pass1<<<NB * NH * NCH, 64, 0, stream>>>(qkvb, decayp, fkv, fk);
    scan_pass2<<<NB * NH, 64, 0, stream>>>(fkv, fk, decayp, ckv, ck,
                                           out + (size_t)ROWS * HID);
    scan_pass3<<<NB * NH * NCH, 64, 0, stream>>>(qkvb, decayp, ckv, ck, attnb);

    // GEMM2: out = attnb @ woutT^T  (f32 out)  grid 64x16 = 1024 blocks
    {
        int nby = ROWS / 128, nbx = HID / 128;
        gemm128<float><<<nby * nbx, 256, 0, stream>>>(
            attnb, woutT, out, ROWS, HID, HID, nby / 8);
    }
}